// Round 1
// baseline (6199.151 us; speedup 1.0000x reference)
//
#include <hip/hip_runtime.h>
#include <math.h>

#define B     64
#define NCAP  64
#define LV    197
#define LT    32
#define C     512
#define NSP   196
#define NKEEP 98
#define HID   102
#define KEEPED 49

// Workspace layout (float element offsets). Total 4,621,120 floats = 18.5 MB.
#define OFF_INV     0                         // B*LV            = 12608
#define OFF_ATTNX   12608                     // B*NSP           = 12544
#define OFF_WSMAT   25152                     // B*NSP*KEEPED    = 614656
#define OFF_CAPN    639808                    // NCAP*LT*C       = 1048576
#define OFF_QI2T    1688384                   // NCAP*LT*C
#define OFF_QT2I    2736960                   // NCAP*LT*C
#define OFF_GLOT    3785536                   // C*NCAP          = 32768
#define OFF_ATTNY   3818304                   // B*NSP*NCAP      = 802816

__device__ __forceinline__ float gelu_exact(float x) {
    return 0.5f * x * (1.f + erff(x * 0.70710678118654752f));
}

// ---------------------------------------------------------------- img row norms
__global__ __launch_bounds__(64) void k_img_norm(const float* __restrict__ img,
                                                 float* __restrict__ inv_img) {
    int r = blockIdx.x, t = threadIdx.x;
    const float* row = img + (size_t)r * C;
    float ss = 0.f;
    for (int c = t; c < C; c += 64) { float v = row[c]; ss += v * v; }
    for (int o = 32; o > 0; o >>= 1) ss += __shfl_down(ss, o);
    if (t == 0) inv_img[r] = 1.f / fmaxf(sqrtf(ss), 1e-12f);
}

// ---------------------------------------------------------------- caption norms
__global__ __launch_bounds__(64) void k_cap_norm(const float* __restrict__ cap,
                                                 float* __restrict__ capn,
                                                 float* __restrict__ gloT) {
    int i = blockIdx.x, tt = blockIdx.y, t = threadIdx.x;
    const float* row = cap + ((size_t)i * LT + tt) * C;
    float v[8]; float ss = 0.f;
#pragma unroll
    for (int q = 0; q < 8; ++q) { v[q] = row[t + 64 * q]; ss += v[q] * v[q]; }
    for (int o = 32; o > 0; o >>= 1) ss += __shfl_down(ss, o);
    ss = __shfl(ss, 0);
    float inv = 1.f / fmaxf(sqrtf(ss), 1e-12f);
    float* orow = capn + ((size_t)i * LT + tt) * C;
#pragma unroll
    for (int q = 0; q < 8; ++q) {
        float n = v[q] * inv;
        orow[t + 64 * q] = n;
        if (tt == 0) gloT[(t + 64 * q) * NCAP + i] = n;   // transposed cap_glo
    }
}

// ---------------------------------------------------------------- qi2t / qt2i projections
__global__ __launch_bounds__(256) void k_qproj(const float* __restrict__ capn,
                                               const float* __restrict__ wi2t,
                                               const float* __restrict__ bi2t,
                                               const float* __restrict__ wt2i,
                                               const float* __restrict__ bt2i,
                                               float* __restrict__ qi2t,
                                               float* __restrict__ qt2i) {
    int i = blockIdx.x, tg = blockIdx.y, t = threadIdx.x;
    __shared__ __align__(16) float xr[8][C];
    const float* base = capn + ((size_t)i * LT + tg * 8) * C;
    for (int f = t; f < 8 * C; f += 256) xr[f >> 9][f & 511] = base[f];
    __syncthreads();
    int j0 = t, j1 = t + 256;
    for (int mtx = 0; mtx < 2; ++mtx) {
        const float* W  = mtx ? wt2i : wi2t;
        const float* bb = mtx ? bt2i : bi2t;
        float* Q        = mtx ? qt2i : qi2t;
        float a0[8], a1[8];
        float bj0 = bb[j0], bj1 = bb[j1];
#pragma unroll
        for (int r = 0; r < 8; ++r) { a0[r] = bj0; a1[r] = bj1; }
        for (int c = 0; c < C; ++c) {
            float w0 = W[c * C + j0], w1v = W[c * C + j1];
#pragma unroll
            for (int r = 0; r < 8; ++r) {
                a0[r] += xr[r][c] * w0;
                a1[r] += xr[r][c] * w1v;
            }
        }
#pragma unroll
        for (int r = 0; r < 8; ++r) {
            Q[((size_t)i * LT + tg * 8 + r) * C + j0] = a0[r];
            Q[((size_t)i * LT + tg * 8 + r) * C + j1] = a1[r];
        }
    }
}

// ---------------------------------------------------------------- LN -> w1 -> gelu -> w2 (per spatial row) + attn_x
__global__ __launch_bounds__(256) void k_img_row(const float* __restrict__ img,
                                                 const float* __restrict__ inv_img,
                                                 const float* __restrict__ gamw,
                                                 const float* __restrict__ betw,
                                                 const float* __restrict__ w1,
                                                 const float* __restrict__ b1,
                                                 const float* __restrict__ w2,
                                                 const float* __restrict__ b2,
                                                 const float* __restrict__ scale_p,
                                                 float* __restrict__ attn_x,
                                                 float* __restrict__ WsM) {
    int b = blockIdx.x, s0 = blockIdx.y * 8, t = threadIdx.x;
    int R = NSP - s0; if (R > 8) R = 8;
    __shared__ __align__(16) float lnr[8][C];
    __shared__ float HH[8][HID + 2];
    __shared__ float redm[8][3];

    // phase 1: 32-lane group g handles row g: stage + sums (sum, sumsq, dot-with-cls)
    int g = t >> 5, lane = t & 31;
    if (g < R) {
        const float* row = img + ((size_t)b * LV + 1 + s0 + g) * C;
        const float* cls = img + (size_t)b * LV * C;
        float sm = 0.f, ss = 0.f, dd = 0.f;
        for (int c = lane; c < C; c += 32) {
            float v = row[c];
            sm += v; ss += v * v; dd += v * cls[c];
            lnr[g][c] = v;
        }
        for (int o = 16; o > 0; o >>= 1) {
            sm += __shfl_down(sm, o, 32);
            ss += __shfl_down(ss, o, 32);
            dd += __shfl_down(dd, o, 32);
        }
        if (lane == 0) { redm[g][0] = sm; redm[g][1] = ss; redm[g][2] = dd; }
    }
    __syncthreads();
    // LN in place
    for (int f = t; f < R * C; f += 256) {
        int rr = f >> 9, c = f & 511;
        float mean = redm[rr][0] * (1.f / C);
        float var  = redm[rr][1] * (1.f / C) - mean * mean;
        float rstd = 1.f / sqrtf(var + 1e-5f);
        lnr[rr][c] = (lnr[rr][c] - mean) * rstd * gamw[c] + betw[c];
    }
    if (t < R) {
        float inv0 = inv_img[b * LV];
        float invs = inv_img[b * LV + 1 + s0 + t];
        attn_x[b * NSP + s0 + t] = redm[t][2] * inv0 * invs;
    }
    __syncthreads();
    // phase 2: h = gelu(ln @ w1 + b1); w1 column read once per block for 8 rows
    if (t < HID) {
        float acc[8];
#pragma unroll
        for (int r = 0; r < 8; ++r) acc[r] = b1[t];
        for (int c = 0; c < C; ++c) {
            float w = w1[c * HID + t];
#pragma unroll
            for (int r = 0; r < 8; ++r) acc[r] += lnr[r][c] * w;
        }
#pragma unroll
        for (int r = 0; r < 8; ++r) HH[r][t] = gelu_exact(acc[r]);
    }
    __syncthreads();
    // phase 3: Ws[b,s,k] = (h @ w2 + b2)[k] * aggr_scale
    float scale = scale_p[0];
    if (t < 196) {
        int k = t % 49, rh = t / 49;
        for (int rr = rh; rr < 8; rr += 4) {
            if (rr < R) {
                float a = b2[k];
                for (int h = 0; h < HID; ++h) a += HH[rr][h] * w2[h * 49 + k];
                WsM[((size_t)b * NSP + s0 + rr) * 49 + k] = a * scale;
            }
        }
    }
}

// ---------------------------------------------------------------- attn_y[b,s,i] = cap_glo_i . img_sp_norm[b,s]
__global__ __launch_bounds__(64) void k_attn_y(const float* __restrict__ img,
                                               const float* __restrict__ inv_img,
                                               const float* __restrict__ gloT,
                                               float* __restrict__ attn_y) {
    int b = blockIdx.x, s0 = blockIdx.y * 8, t = threadIdx.x;
    int R = NSP - s0; if (R > 8) R = 8;
    __shared__ __align__(16) float xr[8][C];
    for (int rr = 0; rr < R; ++rr) {
        float inv = inv_img[b * LV + 1 + s0 + rr];
        const float* row = img + ((size_t)b * LV + 1 + s0 + rr) * C;
        for (int c = t; c < C; c += 64) xr[rr][c] = row[c] * inv;
    }
    __syncthreads();
    float acc[8] = {0, 0, 0, 0, 0, 0, 0, 0};
    for (int c4 = 0; c4 < C / 4; ++c4) {
        float g0 = gloT[(c4 * 4 + 0) * NCAP + t];
        float g1 = gloT[(c4 * 4 + 1) * NCAP + t];
        float g2 = gloT[(c4 * 4 + 2) * NCAP + t];
        float g3 = gloT[(c4 * 4 + 3) * NCAP + t];
#pragma unroll
        for (int r = 0; r < 8; ++r) {
            float4 xv = ((const float4*)xr[r])[c4];
            acc[r] += xv.x * g0 + xv.y * g1 + xv.z * g2 + xv.w * g3;
        }
    }
    for (int rr = 0; rr < R; ++rr)
        attn_y[((size_t)b * NSP + s0 + rr) * NCAP + t] = acc[rr];
}

// ---------------------------------------------------------------- main per-pair kernel
__global__ __launch_bounds__(256, 2) void k_main(const float* __restrict__ img,
                                                 const float* __restrict__ inv_img,
                                                 const float* __restrict__ attn_x,
                                                 const float* __restrict__ attn_y,
                                                 const float* __restrict__ WsM,
                                                 const float* __restrict__ capn,
                                                 const float* __restrict__ qi2t,
                                                 const float* __restrict__ qt2i,
                                                 const float* __restrict__ temp_p,
                                                 float* __restrict__ out) {
    int b = blockIdx.x, i = blockIdx.y, t = threadIdx.x;
    __shared__ float scoreS[NSP];
    __shared__ int   keepI[NKEEP];
    __shared__ int   nonkI[NKEEP];
    __shared__ float pnk[NKEEP];
    __shared__ __align__(16) float P[NKEEP * 52];   // softmaxed Ws; reused as U[96][52]
    __shared__ float tokc[51 * 33];                 // sel_tok column chunk; reused for softmax stats
    __shared__ float Qt[32 * 97];                   // Q K-chunk tile
    __shared__ float invA[49];
    __shared__ float redb[200];
    __shared__ float bcast[2];

    // 1. scores
    if (t < NSP) scoreS[t] = attn_x[b * NSP + t] + attn_y[(b * NSP + t) * NCAP + i];
    __syncthreads();
    // 2. stable-descending rank -> top-98 partition (order inside sets is irrelevant downstream)
    if (t < NSP) {
        float sv = scoreS[t];
        int r = 0;
        for (int u = 0; u < NSP; ++u) {
            float o = scoreS[u];
            r += (o > sv) || (o == sv && u < t);
        }
        if (r < NKEEP) keepI[r] = t; else nonkI[r - NKEEP] = t;
    }
    __syncthreads();
    // 3. nonkeep softmax weights (unnormalized; sel_tok renorm makes scale irrelevant) + extra in regs
    float m = -1e30f;
    for (int j = 0; j < NKEEP; ++j) m = fmaxf(m, scoreS[nonkI[j]]);
    if (t < NKEEP) pnk[t] = expf(scoreS[nonkI[t]] - m);
    __syncthreads();
    float e0 = 0.f, e1 = 0.f;
    for (int j = 0; j < NKEEP; ++j) {
        int s2 = nonkI[j];
        const float* row = img + ((size_t)b * LV + 1 + s2) * C;
        float w = pnk[j];
        e0 += w * row[t];
        e1 += w * row[t + 256];
    }
    // 4. gather kept Ws and per-k softmax over the 98 kept tokens (unnormalized)
    for (int f = t; f < NKEEP * 49; f += 256) {
        int j = f / 49, k = f - j * 49;
        P[j * 52 + k] = WsM[((size_t)b * NSP + keepI[j]) * 49 + k];
    }
    __syncthreads();
    if (t < 49) {
        float mk = -1e30f;
        for (int j = 0; j < NKEEP; ++j) mk = fmaxf(mk, P[j * 52 + t]);
        for (int j = 0; j < NKEEP; ++j) P[j * 52 + t] = expf(P[j * 52 + t] - mk);
    }
    __syncthreads();
    // 5. aggr = P @ sel; thread t owns columns c=t and c=t+256, 49 k-accumulators each
    float acc0[49], acc1[49];
#pragma unroll
    for (int k = 0; k < 49; ++k) { acc0[k] = 0.f; acc1[k] = 0.f; }
    for (int j = 0; j < NKEEP; ++j) {
        int s2 = keepI[j];
        const float* row = img + ((size_t)b * LV + 1 + s2) * C;
        float v0 = row[t], v1 = row[t + 256];
        const float4* p4 = (const float4*)(P + j * 52);
#pragma unroll
        for (int q = 0; q < 12; ++q) {
            float4 p = p4[q];
            acc0[q * 4 + 0] += p.x * v0; acc1[q * 4 + 0] += p.x * v1;
            acc0[q * 4 + 1] += p.y * v0; acc1[q * 4 + 1] += p.y * v1;
            acc0[q * 4 + 2] += p.z * v0; acc1[q * 4 + 2] += p.z * v1;
            acc0[q * 4 + 3] += p.w * v0; acc1[q * 4 + 3] += p.w * v1;
        }
        float pl = P[j * 52 + 48];
        acc0[48] += pl * v0; acc1[48] += pl * v1;
    }
    // 6. row norms of aggr (49) and extra
    int wv = t >> 6;
#pragma unroll
    for (int k = 0; k < 49; ++k) {
        float v = acc0[k] * acc0[k] + acc1[k] * acc1[k];
        for (int o = 32; o > 0; o >>= 1) v += __shfl_down(v, o);
        if ((t & 63) == 0) redb[wv * 49 + k] = v;
    }
    {
        float v = e0 * e0 + e1 * e1;
        for (int o = 32; o > 0; o >>= 1) v += __shfl_down(v, o);
        if ((t & 63) == 0) redb[196 + wv] = v;
    }
    __syncthreads();
    if (t < 49) {
        float s = redb[t] + redb[49 + t] + redb[98 + t] + redb[147 + t];
        invA[t] = 1.f / fmaxf(sqrtf(s), 1e-12f);
    }
    if (t == 0) {
        float s = redb[196] + redb[197] + redb[198] + redb[199];
        bcast[0] = 1.f / fmaxf(sqrtf(s), 1e-12f);
    }
    __syncthreads();
    float invE = bcast[0];
    float invC = inv_img[b * LV];
    // 7. U = [cap_norm; qi2t; qt2i](96 x C) @ sel_tok^T(C x 51), chunked over C by 32
    float uacc[6][4];
#pragma unroll
    for (int a = 0; a < 6; ++a)
#pragma unroll
        for (int e = 0; e < 4; ++e) uacc[a][e] = 0.f;
    int tx = t & 15, ty = t >> 4;
    const float* q0 = capn + (size_t)i * LT * C;
    const float* q1 = qi2t + (size_t)i * LT * C;
    const float* q2 = qt2i + (size_t)i * LT * C;
    for (int c0 = 0; c0 < C; c0 += 32) {
        int cc = (c0 < 256) ? (t - c0) : (t - (c0 - 256));
        if (cc >= 0 && cc < 32) {
            bool hi = (c0 >= 256);
            int c = c0 + cc;
            tokc[0 * 33 + cc] = img[(size_t)b * LV * C + c] * invC;
#pragma unroll
            for (int k = 0; k < 49; ++k)
                tokc[(1 + k) * 33 + cc] = (hi ? acc1[k] : acc0[k]) * invA[k];
            tokc[50 * 33 + cc] = (hi ? e1 : e0) * invE;
        }
        for (int f = t; f < 32 * 96; f += 256) {
            int cc2 = f & 31, q = f >> 5;
            const float* qr = (q < 32) ? (q0 + (size_t)q * C)
                           : (q < 64) ? (q1 + (size_t)(q - 32) * C)
                                      : (q2 + (size_t)(q - 64) * C);
            Qt[cc2 * 97 + q] = qr[c0 + cc2];
        }
        __syncthreads();
        for (int cc2 = 0; cc2 < 32; ++cc2) {
            float bq[6], bl[4];
#pragma unroll
            for (int a = 0; a < 6; ++a) bq[a] = Qt[cc2 * 97 + ty + 16 * a];
#pragma unroll
            for (int e = 0; e < 4; ++e) {
                int l = tx + 16 * e;
                bl[e] = (l < 51) ? tokc[l * 33 + cc2] : 0.f;
            }
#pragma unroll
            for (int a = 0; a < 6; ++a)
#pragma unroll
                for (int e = 0; e < 4; ++e) uacc[a][e] += bq[a] * bl[e];
        }
        __syncthreads();
    }
    // 8. write U (rows: 0-31 c2i-input, 32-63 i2t logits, 64-95 t2i logits) into P region
#pragma unroll
    for (int a = 0; a < 6; ++a) {
        int q = ty + 16 * a;
#pragma unroll
        for (int e = 0; e < 4; ++e) {
            int l = tx + 16 * e;
            if (l < 51) P[q * 52 + l] = uacc[a][e];
        }
    }
    __syncthreads();
    // 9. softmax stats (cols of U1 over t; rows of U2 over l)
    float invT = 1.f / temp_p[0];
    float* colM = tokc;        float* colZ = tokc + 64;
    float* rowM = tokc + 128;  float* rowZ = tokc + 192;
    if (t < 51) {
        float mm = -1e30f;
        for (int u = 0; u < LT; ++u) mm = fmaxf(mm, P[(32 + u) * 52 + t] * invT);
        float z = 0.f;
        for (int u = 0; u < LT; ++u) z += expf(P[(32 + u) * 52 + t] * invT - mm);
        colM[t] = mm; colZ[t] = 1.f / z;
    }
    if (t >= 64 && t < 96) {
        int u = t - 64;
        float mm = -1e30f;
        for (int l = 0; l < 51; ++l) mm = fmaxf(mm, P[(64 + u) * 52 + l] * invT);
        float z = 0.f;
        for (int l = 0; l < 51; ++l) z += expf(P[(64 + u) * 52 + l] * invT - mm);
        rowM[u] = mm; rowZ[u] = 1.f / z;
    }
    __syncthreads();
    // 10. final reduction: sum a_i2t*c2i/51 + a_t2i*c2i/32
    float part = 0.f;
    for (int f = t; f < LT * 51; f += 256) {
        int u = f / 51, l = f - u * 51;
        float u0 = P[u * 52 + l];
        float c2 = (u0 > 0.f) ? u0 : 0.1f * u0;
        float av = expf(P[(32 + u) * 52 + l] * invT - colM[l]) * colZ[l];
        float bv = expf(P[(64 + u) * 52 + l] * invT - rowM[u]) * rowZ[u];
        part += c2 * (av * (1.f / 51.f) + bv * (1.f / 32.f));
    }
    for (int o = 32; o > 0; o >>= 1) part += __shfl_down(part, o);
    if ((t & 63) == 0) redb[t >> 6] = part;
    __syncthreads();
    if (t == 0) out[b * NCAP + i] = redb[0] + redb[1] + redb[2] + redb[3];
}

extern "C" void kernel_launch(void* const* d_in, const int* in_sizes, int n_in,
                              void* d_out, int out_size, void* d_ws, size_t ws_size,
                              hipStream_t stream) {
    const float* img        = (const float*)d_in[0];
    const float* cap        = (const float*)d_in[1];
    const float* gamw       = (const float*)d_in[3];
    const float* betw       = (const float*)d_in[4];
    const float* w1         = (const float*)d_in[5];
    const float* b1         = (const float*)d_in[6];
    const float* w2         = (const float*)d_in[7];
    const float* b2         = (const float*)d_in[8];
    const float* aggr_scale = (const float*)d_in[9];
    const float* wi2t       = (const float*)d_in[10];
    const float* bi2t       = (const float*)d_in[11];
    const float* wt2i       = (const float*)d_in[12];
    const float* bt2i       = (const float*)d_in[13];
    const float* temp       = (const float*)d_in[14];
    float* out = (float*)d_out;

    float* ws      = (float*)d_ws;
    float* inv_img = ws + OFF_INV;
    float* attn_x  = ws + OFF_ATTNX;
    float* WsM     = ws + OFF_WSMAT;
    float* capn    = ws + OFF_CAPN;
    float* qi2t    = ws + OFF_QI2T;
    float* qt2i    = ws + OFF_QT2I;
    float* gloT    = ws + OFF_GLOT;
    float* attn_y  = ws + OFF_ATTNY;

    k_img_norm<<<dim3(B * LV), dim3(64), 0, stream>>>(img, inv_img);
    k_cap_norm<<<dim3(NCAP, LT), dim3(64), 0, stream>>>(cap, capn, gloT);
    k_qproj<<<dim3(NCAP, 4), dim3(256), 0, stream>>>(capn, wi2t, bi2t, wt2i, bt2i, qi2t, qt2i);
    k_img_row<<<dim3(B, 25), dim3(256), 0, stream>>>(img, inv_img, gamw, betw, w1, b1, w2, b2,
                                                     aggr_scale, attn_x, WsM);
    k_attn_y<<<dim3(B, 25), dim3(64), 0, stream>>>(img, inv_img, gloT, attn_y);
    k_main<<<dim3(B, NCAP), dim3(256), 0, stream>>>(img, inv_img, attn_x, attn_y, WsM,
                                                    capn, qi2t, qt2i, temp, out);
}

// Round 2
// 2897.952 us; speedup vs baseline: 2.1391x; 2.1391x over previous
//
#include <hip/hip_runtime.h>
#include <math.h>

#define B     64
#define NCAP  64
#define LV    197
#define LT    32
#define C     512
#define NSP   196
#define NKEEP 98
#define HID   102
#define KEEPED 49

// Workspace layout (float element offsets).
#define OFF_INV     0                         // B*LV            = 12608
#define OFF_ATTNX   12608                     // B*NSP           = 12544
#define OFF_WSMAT   25152                     // B*NSP*KEEPED    = 614656
#define OFF_CAPN    639808                    // NCAP*LT*C       = 1048576
#define OFF_QI2T    1688384                   // NCAP*LT*C
#define OFF_QT2I    2736960                   // NCAP*LT*C
#define OFF_GLOT    3785536                   // C*NCAP          = 32768
#define OFF_ATTNY   3818304                   // B*NSP*NCAP      = 802816
#define OFF_KEEP    4621120                   // 4096*98 ints
#define OFF_NON     5022528                   // 4096*98 ints
#define OFF_PNK     5423936                   // 4096*98 floats
#define OFF_GP      5825344                   // 4096*98*52 floats = 20,873,216
// total = 26,698,560 floats = 106.8 MB

__device__ __forceinline__ float gelu_exact(float x) {
    return 0.5f * x * (1.f + erff(x * 0.70710678118654752f));
}

// ---------------------------------------------------------------- img row norms
__global__ __launch_bounds__(64) void k_img_norm(const float* __restrict__ img,
                                                 float* __restrict__ inv_img) {
    int r = blockIdx.x, t = threadIdx.x;
    const float* row = img + (size_t)r * C;
    float ss = 0.f;
    for (int c = t; c < C; c += 64) { float v = row[c]; ss += v * v; }
    for (int o = 32; o > 0; o >>= 1) ss += __shfl_down(ss, o);
    if (t == 0) inv_img[r] = 1.f / fmaxf(sqrtf(ss), 1e-12f);
}

// ---------------------------------------------------------------- caption norms
__global__ __launch_bounds__(64) void k_cap_norm(const float* __restrict__ cap,
                                                 float* __restrict__ capn,
                                                 float* __restrict__ gloT) {
    int i = blockIdx.x, tt = blockIdx.y, t = threadIdx.x;
    const float* row = cap + ((size_t)i * LT + tt) * C;
    float v[8]; float ss = 0.f;
#pragma unroll
    for (int q = 0; q < 8; ++q) { v[q] = row[t + 64 * q]; ss += v[q] * v[q]; }
    for (int o = 32; o > 0; o >>= 1) ss += __shfl_down(ss, o);
    ss = __shfl(ss, 0);
    float inv = 1.f / fmaxf(sqrtf(ss), 1e-12f);
    float* orow = capn + ((size_t)i * LT + tt) * C;
#pragma unroll
    for (int q = 0; q < 8; ++q) {
        float n = v[q] * inv;
        orow[t + 64 * q] = n;
        if (tt == 0) gloT[(t + 64 * q) * NCAP + i] = n;   // transposed cap_glo
    }
}

// ---------------------------------------------------------------- qi2t / qt2i projections
__global__ __launch_bounds__(256) void k_qproj(const float* __restrict__ capn,
                                               const float* __restrict__ wi2t,
                                               const float* __restrict__ bi2t,
                                               const float* __restrict__ wt2i,
                                               const float* __restrict__ bt2i,
                                               float* __restrict__ qi2t,
                                               float* __restrict__ qt2i) {
    int i = blockIdx.x, tg = blockIdx.y, t = threadIdx.x;
    __shared__ __align__(16) float xr[8][C];
    const float* base = capn + ((size_t)i * LT + tg * 8) * C;
    for (int f = t; f < 8 * C; f += 256) xr[f >> 9][f & 511] = base[f];
    __syncthreads();
    int j0 = t, j1 = t + 256;
    for (int mtx = 0; mtx < 2; ++mtx) {
        const float* W  = mtx ? wt2i : wi2t;
        const float* bb = mtx ? bt2i : bi2t;
        float* Q        = mtx ? qt2i : qi2t;
        float a0[8], a1[8];
        float bj0 = bb[j0], bj1 = bb[j1];
#pragma unroll
        for (int r = 0; r < 8; ++r) { a0[r] = bj0; a1[r] = bj1; }
        for (int c = 0; c < C; ++c) {
            float w0 = W[c * C + j0], w1v = W[c * C + j1];
#pragma unroll
            for (int r = 0; r < 8; ++r) {
                a0[r] += xr[r][c] * w0;
                a1[r] += xr[r][c] * w1v;
            }
        }
#pragma unroll
        for (int r = 0; r < 8; ++r) {
            Q[((size_t)i * LT + tg * 8 + r) * C + j0] = a0[r];
            Q[((size_t)i * LT + tg * 8 + r) * C + j1] = a1[r];
        }
    }
}

// ---------------------------------------------------------------- LN -> w1 -> gelu -> w2 (per spatial row) + attn_x
__global__ __launch_bounds__(256) void k_img_row(const float* __restrict__ img,
                                                 const float* __restrict__ inv_img,
                                                 const float* __restrict__ gamw,
                                                 const float* __restrict__ betw,
                                                 const float* __restrict__ w1,
                                                 const float* __restrict__ b1,
                                                 const float* __restrict__ w2,
                                                 const float* __restrict__ b2,
                                                 const float* __restrict__ scale_p,
                                                 float* __restrict__ attn_x,
                                                 float* __restrict__ WsM) {
    int b = blockIdx.x, s0 = blockIdx.y * 8, t = threadIdx.x;
    int R = NSP - s0; if (R > 8) R = 8;
    __shared__ __align__(16) float lnr[8][C];
    __shared__ float HH[8][HID + 2];
    __shared__ float redm[8][3];

    int g = t >> 5, lane = t & 31;
    if (g < R) {
        const float* row = img + ((size_t)b * LV + 1 + s0 + g) * C;
        const float* cls = img + (size_t)b * LV * C;
        float sm = 0.f, ss = 0.f, dd = 0.f;
        for (int c = lane; c < C; c += 32) {
            float v = row[c];
            sm += v; ss += v * v; dd += v * cls[c];
            lnr[g][c] = v;
        }
        for (int o = 16; o > 0; o >>= 1) {
            sm += __shfl_down(sm, o, 32);
            ss += __shfl_down(ss, o, 32);
            dd += __shfl_down(dd, o, 32);
        }
        if (lane == 0) { redm[g][0] = sm; redm[g][1] = ss; redm[g][2] = dd; }
    }
    __syncthreads();
    for (int f = t; f < R * C; f += 256) {
        int rr = f >> 9, c = f & 511;
        float mean = redm[rr][0] * (1.f / C);
        float var  = redm[rr][1] * (1.f / C) - mean * mean;
        float rstd = 1.f / sqrtf(var + 1e-5f);
        lnr[rr][c] = (lnr[rr][c] - mean) * rstd * gamw[c] + betw[c];
    }
    if (t < R) {
        float inv0 = inv_img[b * LV];
        float invs = inv_img[b * LV + 1 + s0 + t];
        attn_x[b * NSP + s0 + t] = redm[t][2] * inv0 * invs;
    }
    __syncthreads();
    if (t < HID) {
        float acc[8];
#pragma unroll
        for (int r = 0; r < 8; ++r) acc[r] = b1[t];
        for (int c = 0; c < C; ++c) {
            float w = w1[c * HID + t];
#pragma unroll
            for (int r = 0; r < 8; ++r) acc[r] += lnr[r][c] * w;
        }
#pragma unroll
        for (int r = 0; r < 8; ++r) HH[r][t] = gelu_exact(acc[r]);
    }
    __syncthreads();
    float scale = scale_p[0];
    if (t < 196) {
        int k = t % 49, rh = t / 49;
        for (int rr = rh; rr < 8; rr += 4) {
            if (rr < R) {
                float a = b2[k];
                for (int h = 0; h < HID; ++h) a += HH[rr][h] * w2[h * 49 + k];
                WsM[((size_t)b * NSP + s0 + rr) * 49 + k] = a * scale;
            }
        }
    }
}

// ---------------------------------------------------------------- attn_y[b,s,i] = cap_glo_i . img_sp_norm[b,s]
__global__ __launch_bounds__(64) void k_attn_y(const float* __restrict__ img,
                                               const float* __restrict__ inv_img,
                                               const float* __restrict__ gloT,
                                               float* __restrict__ attn_y) {
    int b = blockIdx.x, s0 = blockIdx.y * 8, t = threadIdx.x;
    int R = NSP - s0; if (R > 8) R = 8;
    __shared__ __align__(16) float xr[8][C];
    for (int rr = 0; rr < R; ++rr) {
        float inv = inv_img[b * LV + 1 + s0 + rr];
        const float* row = img + ((size_t)b * LV + 1 + s0 + rr) * C;
        for (int c = t; c < C; c += 64) xr[rr][c] = row[c] * inv;
    }
    __syncthreads();
    float acc[8] = {0, 0, 0, 0, 0, 0, 0, 0};
    for (int c4 = 0; c4 < C / 4; ++c4) {
        float g0 = gloT[(c4 * 4 + 0) * NCAP + t];
        float g1 = gloT[(c4 * 4 + 1) * NCAP + t];
        float g2 = gloT[(c4 * 4 + 2) * NCAP + t];
        float g3 = gloT[(c4 * 4 + 3) * NCAP + t];
#pragma unroll
        for (int r = 0; r < 8; ++r) {
            float4 xv = ((const float4*)xr[r])[c4];
            acc[r] += xv.x * g0 + xv.y * g1 + xv.z * g2 + xv.w * g3;
        }
    }
    for (int rr = 0; rr < R; ++rr)
        attn_y[((size_t)b * NSP + s0 + rr) * NCAP + t] = acc[rr];
}

// ---------------------------------------------------------------- per-pair prep: rank, gather, softmax -> global
__global__ __launch_bounds__(256) void k_prep(const float* __restrict__ attn_x,
                                              const float* __restrict__ attn_y,
                                              const float* __restrict__ WsM,
                                              int* __restrict__ gKeep,
                                              int* __restrict__ gNon,
                                              float* __restrict__ gPnk,
                                              float* __restrict__ gP) {
    int i = blockIdx.x, b = blockIdx.y, t = threadIdx.x;
    int pair = b * NCAP + i;
    __shared__ float scoreS[NSP];
    __shared__ int   keepL[NKEEP];
    __shared__ int   nonL[NKEEP];
    __shared__ float snon[NKEEP];
    __shared__ float mk[KEEPED];
    __shared__ float bcast[1];

    if (t < NSP) scoreS[t] = attn_x[b * NSP + t] + attn_y[(size_t)(b * NSP + t) * NCAP + i];
    __syncthreads();
    // stable-descending rank -> top-98 partition
    if (t < NSP) {
        float sv = scoreS[t];
        int r = 0;
        for (int u = 0; u < NSP; ++u) {
            float o = scoreS[u];
            r += (o > sv) || (o == sv && u < t);
        }
        if (r < NKEEP) keepL[r] = t;
        else { nonL[r - NKEEP] = t; snon[r - NKEEP] = sv; }
    }
    __syncthreads();
    if (t == 0) {
        float m = -1e30f;
        for (int j = 0; j < NKEEP; ++j) m = fmaxf(m, snon[j]);
        bcast[0] = m;
    }
    __syncthreads();
    if (t < NKEEP) {
        gKeep[pair * NKEEP + t] = keepL[t];
        gNon[pair * NKEEP + t]  = nonL[t];
        gPnk[pair * NKEEP + t]  = expf(snon[t] - bcast[0]);
    }
    if (t < KEEPED) {
        float m2 = -1e30f;
        for (int j = 0; j < NKEEP; ++j)
            m2 = fmaxf(m2, WsM[((size_t)b * NSP + keepL[j]) * KEEPED + t]);
        mk[t] = m2;
    }
    __syncthreads();
    float* Pm = gP + (size_t)pair * NKEEP * 52;
    for (int f = t; f < NKEEP * KEEPED; f += 256) {
        int j = f / KEEPED, k = f - j * KEEPED;
        Pm[j * 52 + k] = expf(WsM[((size_t)b * NSP + keepL[j]) * KEEPED + k] - mk[k]);
    }
}

// ---------------------------------------------------------------- main per-pair kernel (512 thr, thread t owns column t)
__global__ __launch_bounds__(512, 4) void k_main(const float* __restrict__ img,
                                                 const float* __restrict__ inv_img,
                                                 const int* __restrict__ gKeep,
                                                 const int* __restrict__ gNon,
                                                 const float* __restrict__ gPnk,
                                                 const float* __restrict__ gP,
                                                 const float* __restrict__ capn,
                                                 const float* __restrict__ qi2t,
                                                 const float* __restrict__ qt2i,
                                                 const float* __restrict__ temp_p,
                                                 float* __restrict__ out) {
    int i = blockIdx.x, b = blockIdx.y, t = threadIdx.x;
    int pair = b * NCAP + i;
    int lane = t & 63;

    __shared__ float tokL[128 * 53];     // 27.1 KB, sel_tok chunk, [cc][53]
    __shared__ float Ulds[96 * 52];      // 20.0 KB
    __shared__ float wpart[8 * 50];
    __shared__ float invA[KEEPED];
    __shared__ float sc[2];
    __shared__ float colM[51], colZ[51], rowM[32], rowZ[32];

    const int*   keep = gKeep + pair * NKEEP;
    const int*   nonk = gNon + pair * NKEEP;
    const float* pnk  = gPnk + pair * NKEEP;
    const float* Pm   = gP + (size_t)pair * NKEEP * 52;
    const float* imgb = img + (size_t)b * LV * C;

    float clsv = imgb[t];

    // ---- extra[c=t]: nonkeep softmax-weighted sum (weights scalar via s_load)
    float e = 0.f;
#pragma unroll 4
    for (int j = 0; j < NKEEP; ++j) {
        int s2 = nonk[j];                 // wave-uniform
        e += pnk[j] * imgb[(size_t)(1 + s2) * C + t];
    }

    // ---- aggr[k][c=t]: P rows scalar (s_load -> SGPR-source fmac), sel column vector load
    float acc[KEEPED];
#pragma unroll
    for (int k = 0; k < KEEPED; ++k) acc[k] = 0.f;
#pragma unroll 4
    for (int j = 0; j < NKEEP; ++j) {
        int s2 = keep[j];                 // wave-uniform
        float v = imgb[(size_t)(1 + s2) * C + t];
        const float* pr = Pm + j * 52;    // wave-uniform row
#pragma unroll
        for (int k = 0; k < KEEPED; ++k) acc[k] += pr[k] * v;
    }

    // ---- row norms: reduce acc[k]^2 and e^2 over all 512 threads
    int w = t >> 6;
#pragma unroll
    for (int k = 0; k < KEEPED; ++k) {
        float v = acc[k] * acc[k];
        for (int o = 32; o > 0; o >>= 1) v += __shfl_down(v, o);
        if (lane == 0) wpart[w * 50 + k] = v;
    }
    {
        float v = e * e;
        for (int o = 32; o > 0; o >>= 1) v += __shfl_down(v, o);
        if (lane == 0) wpart[w * 50 + 49] = v;
    }
    __syncthreads();
    if (t < 50) {
        float s = 0.f;
#pragma unroll
        for (int ww = 0; ww < 8; ++ww) s += wpart[ww * 50 + t];
        float r = 1.f / fmaxf(sqrtf(s), 1e-12f);
        if (t < KEEPED) invA[t] = r; else sc[0] = r;
    }
    __syncthreads();
    float invE = sc[0];
    float invC = inv_img[b * LV];

    // ---- U = [capn; qi2t; qt2i](96 x C) @ sel_tok^T(C x 51)
    // wave w owns 12 q-rows (scalar loads); lane l owns sel_tok column l (LDS)
    int wu = __builtin_amdgcn_readfirstlane(t >> 6);
    const float* rowp[12];
#pragma unroll
    for (int r = 0; r < 12; ++r) {
        int q = wu * 12 + r;
        rowp[r] = (q < 32) ? (capn + ((size_t)i * LT + q) * C)
                : (q < 64) ? (qi2t + ((size_t)i * LT + q - 32) * C)
                           : (qt2i + ((size_t)i * LT + q - 64) * C);
    }
    float uacc[12];
#pragma unroll
    for (int r = 0; r < 12; ++r) uacc[r] = 0.f;
    int lidx = (lane < 51) ? lane : 0;

    for (int c0 = 0; c0 < C; c0 += 128) {
        int cc = t - c0;
        if (cc >= 0 && cc < 128) {
            float* row = tokL + cc * 53;
            row[0] = clsv * invC;
#pragma unroll
            for (int k = 0; k < KEEPED; ++k) row[1 + k] = acc[k] * invA[k];
            row[50] = e * invE;
        }
        __syncthreads();
#pragma unroll 4
        for (int c2 = 0; c2 < 128; ++c2) {
            float tv = tokL[c2 * 53 + lidx];
            int c = c0 + c2;
#pragma unroll
            for (int r = 0; r < 12; ++r) uacc[r] += rowp[r][c] * tv;
        }
        __syncthreads();
    }
    if (lane < 51) {
#pragma unroll
        for (int r = 0; r < 12; ++r) Ulds[(wu * 12 + r) * 52 + lane] = uacc[r];
    }
    __syncthreads();

    // ---- softmax stats
    float invT = 1.f / temp_p[0];
    if (t < 51) {
        float mm = -1e30f;
        for (int u = 0; u < LT; ++u) mm = fmaxf(mm, Ulds[(32 + u) * 52 + t] * invT);
        float z = 0.f;
        for (int u = 0; u < LT; ++u) z += expf(Ulds[(32 + u) * 52 + t] * invT - mm);
        colM[t] = mm; colZ[t] = 1.f / z;
    }
    if (t >= 64 && t < 96) {
        int u = t - 64;
        float mm = -1e30f;
        for (int l = 0; l < 51; ++l) mm = fmaxf(mm, Ulds[(64 + u) * 52 + l] * invT);
        float z = 0.f;
        for (int l = 0; l < 51; ++l) z += expf(Ulds[(64 + u) * 52 + l] * invT - mm);
        rowM[u] = mm; rowZ[u] = 1.f / z;
    }
    __syncthreads();

    // ---- final reduction
    float part = 0.f;
    for (int f = t; f < LT * 51; f += 512) {
        int u = f / 51, l = f - u * 51;
        float u0 = Ulds[u * 52 + l];
        float c2 = (u0 > 0.f) ? u0 : 0.1f * u0;
        float av = expf(Ulds[(32 + u) * 52 + l] * invT - colM[l]) * colZ[l];
        float bv = expf(Ulds[(64 + u) * 52 + l] * invT - rowM[u]) * rowZ[u];
        part += c2 * (av * (1.f / 51.f) + bv * (1.f / 32.f));
    }
    for (int o = 32; o > 0; o >>= 1) part += __shfl_down(part, o);
    if (lane == 0) wpart[w] = part;
    __syncthreads();
    if (t == 0) {
        float s = 0.f;
#pragma unroll
        for (int ww = 0; ww < 8; ++ww) s += wpart[ww];
        out[b * NCAP + i] = s;
    }
}

extern "C" void kernel_launch(void* const* d_in, const int* in_sizes, int n_in,
                              void* d_out, int out_size, void* d_ws, size_t ws_size,
                              hipStream_t stream) {
    const float* img        = (const float*)d_in[0];
    const float* cap        = (const float*)d_in[1];
    const float* gamw       = (const float*)d_in[3];
    const float* betw       = (const float*)d_in[4];
    const float* w1         = (const float*)d_in[5];
    const float* b1         = (const float*)d_in[6];
    const float* w2         = (const float*)d_in[7];
    const float* b2         = (const float*)d_in[8];
    const float* aggr_scale = (const float*)d_in[9];
    const float* wi2t       = (const float*)d_in[10];
    const float* bi2t       = (const float*)d_in[11];
    const float* wt2i       = (const float*)d_in[12];
    const float* bt2i       = (const float*)d_in[13];
    const float* temp       = (const float*)d_in[14];
    float* out = (float*)d_out;

    float* ws      = (float*)d_ws;
    float* inv_img = ws + OFF_INV;
    float* attn_x  = ws + OFF_ATTNX;
    float* WsM     = ws + OFF_WSMAT;
    float* capn    = ws + OFF_CAPN;
    float* qi2t    = ws + OFF_QI2T;
    float* qt2i    = ws + OFF_QT2I;
    float* gloT    = ws + OFF_GLOT;
    float* attn_y  = ws + OFF_ATTNY;
    int*   gKeep   = (int*)(ws + OFF_KEEP);
    int*   gNon    = (int*)(ws + OFF_NON);
    float* gPnk    = ws + OFF_PNK;
    float* gP      = ws + OFF_GP;

    k_img_norm<<<dim3(B * LV), dim3(64), 0, stream>>>(img, inv_img);
    k_cap_norm<<<dim3(NCAP, LT), dim3(64), 0, stream>>>(cap, capn, gloT);
    k_qproj<<<dim3(NCAP, 4), dim3(256), 0, stream>>>(capn, wi2t, bi2t, wt2i, bt2i, qi2t, qt2i);
    k_img_row<<<dim3(B, 25), dim3(256), 0, stream>>>(img, inv_img, gamw, betw, w1, b1, w2, b2,
                                                     aggr_scale, attn_x, WsM);
    k_attn_y<<<dim3(B, 25), dim3(64), 0, stream>>>(img, inv_img, gloT, attn_y);
    k_prep<<<dim3(NCAP, B), dim3(256), 0, stream>>>(attn_x, attn_y, WsM, gKeep, gNon, gPnk, gP);
    k_main<<<dim3(NCAP, B), dim3(512), 0, stream>>>(img, inv_img, gKeep, gNon, gPnk, gP,
                                                    capn, qi2t, qt2i, temp, out);
}

// Round 3
// 1437.261 us; speedup vs baseline: 4.3132x; 2.0163x over previous
//
#include <hip/hip_runtime.h>
#include <math.h>

#define B     64
#define NCAP  64
#define LV    197
#define LT    32
#define C     512
#define NSP   196
#define NKEEP 98
#define HID   102
#define KEEPED 49

// Workspace layout (float element offsets).
#define OFF_INV     0                         // B*LV            = 12608
#define OFF_ATTNX   12608                     // B*NSP           = 12544
#define OFF_WSMAT   25152                     // B*NSP*KEEPED    = 614656
#define OFF_CAPN    639808                    // NCAP*LT*C       = 1048576
#define OFF_QI2T    1688384                   // NCAP*LT*C
#define OFF_QT2I    2736960                   // NCAP*LT*C
#define OFF_GLOT    3785536                   // C*NCAP          = 32768
#define OFF_ATTNY   3818304                   // B*NSP*NCAP      = 802816
#define OFF_KEEP    4621120                   // 4096*98 ints
#define OFF_NON     5022528                   // 4096*98 ints
#define OFF_PNK     5423936                   // 4096*98 floats
#define OFF_GP      5825344                   // 4096*98*52 floats
// total = 26,698,560 floats = 106.8 MB

__device__ __forceinline__ float gelu_exact(float x) {
    return 0.5f * x * (1.f + erff(x * 0.70710678118654752f));
}

// ---------------------------------------------------------------- img row norms
__global__ __launch_bounds__(64) void k_img_norm(const float* __restrict__ img,
                                                 float* __restrict__ inv_img) {
    int r = blockIdx.x, t = threadIdx.x;
    const float* row = img + (size_t)r * C;
    float ss = 0.f;
    for (int c = t; c < C; c += 64) { float v = row[c]; ss += v * v; }
    for (int o = 32; o > 0; o >>= 1) ss += __shfl_down(ss, o);
    if (t == 0) inv_img[r] = 1.f / fmaxf(sqrtf(ss), 1e-12f);
}

// ---------------------------------------------------------------- caption norms
__global__ __launch_bounds__(64) void k_cap_norm(const float* __restrict__ cap,
                                                 float* __restrict__ capn,
                                                 float* __restrict__ gloT) {
    int i = blockIdx.x, tt = blockIdx.y, t = threadIdx.x;
    const float* row = cap + ((size_t)i * LT + tt) * C;
    float v[8]; float ss = 0.f;
#pragma unroll
    for (int q = 0; q < 8; ++q) { v[q] = row[t + 64 * q]; ss += v[q] * v[q]; }
    for (int o = 32; o > 0; o >>= 1) ss += __shfl_down(ss, o);
    ss = __shfl(ss, 0);
    float inv = 1.f / fmaxf(sqrtf(ss), 1e-12f);
    float* orow = capn + ((size_t)i * LT + tt) * C;
#pragma unroll
    for (int q = 0; q < 8; ++q) {
        float n = v[q] * inv;
        orow[t + 64 * q] = n;
        if (tt == 0) gloT[(t + 64 * q) * NCAP + i] = n;   // transposed cap_glo
    }
}

// ---------------------------------------------------------------- qi2t / qt2i projections
__global__ __launch_bounds__(256) void k_qproj(const float* __restrict__ capn,
                                               const float* __restrict__ wi2t,
                                               const float* __restrict__ bi2t,
                                               const float* __restrict__ wt2i,
                                               const float* __restrict__ bt2i,
                                               float* __restrict__ qi2t,
                                               float* __restrict__ qt2i) {
    int i = blockIdx.x, tg = blockIdx.y, t = threadIdx.x;
    __shared__ __align__(16) float xr[8][C];
    const float* base = capn + ((size_t)i * LT + tg * 8) * C;
    for (int f = t; f < 8 * C; f += 256) xr[f >> 9][f & 511] = base[f];
    __syncthreads();
    int j0 = t, j1 = t + 256;
    for (int mtx = 0; mtx < 2; ++mtx) {
        const float* W  = mtx ? wt2i : wi2t;
        const float* bb = mtx ? bt2i : bi2t;
        float* Q        = mtx ? qt2i : qi2t;
        float a0[8], a1[8];
        float bj0 = bb[j0], bj1 = bb[j1];
#pragma unroll
        for (int r = 0; r < 8; ++r) { a0[r] = bj0; a1[r] = bj1; }
        for (int c = 0; c < C; ++c) {
            float w0 = W[c * C + j0], w1v = W[c * C + j1];
#pragma unroll
            for (int r = 0; r < 8; ++r) {
                a0[r] += xr[r][c] * w0;
                a1[r] += xr[r][c] * w1v;
            }
        }
#pragma unroll
        for (int r = 0; r < 8; ++r) {
            Q[((size_t)i * LT + tg * 8 + r) * C + j0] = a0[r];
            Q[((size_t)i * LT + tg * 8 + r) * C + j1] = a1[r];
        }
    }
}

// ---------------------------------------------------------------- LN -> w1 -> gelu -> w2 (per spatial row) + attn_x
__global__ __launch_bounds__(256) void k_img_row(const float* __restrict__ img,
                                                 const float* __restrict__ inv_img,
                                                 const float* __restrict__ gamw,
                                                 const float* __restrict__ betw,
                                                 const float* __restrict__ w1,
                                                 const float* __restrict__ b1,
                                                 const float* __restrict__ w2,
                                                 const float* __restrict__ b2,
                                                 const float* __restrict__ scale_p,
                                                 float* __restrict__ attn_x,
                                                 float* __restrict__ WsM) {
    int b = blockIdx.x, s0 = blockIdx.y * 8, t = threadIdx.x;
    int R = NSP - s0; if (R > 8) R = 8;
    __shared__ __align__(16) float lnr[8][C];
    __shared__ float HH[8][HID + 2];
    __shared__ float redm[8][3];

    int g = t >> 5, lane = t & 31;
    if (g < R) {
        const float* row = img + ((size_t)b * LV + 1 + s0 + g) * C;
        const float* cls = img + (size_t)b * LV * C;
        float sm = 0.f, ss = 0.f, dd = 0.f;
        for (int c = lane; c < C; c += 32) {
            float v = row[c];
            sm += v; ss += v * v; dd += v * cls[c];
            lnr[g][c] = v;
        }
        for (int o = 16; o > 0; o >>= 1) {
            sm += __shfl_down(sm, o, 32);
            ss += __shfl_down(ss, o, 32);
            dd += __shfl_down(dd, o, 32);
        }
        if (lane == 0) { redm[g][0] = sm; redm[g][1] = ss; redm[g][2] = dd; }
    }
    __syncthreads();
    for (int f = t; f < R * C; f += 256) {
        int rr = f >> 9, c = f & 511;
        float mean = redm[rr][0] * (1.f / C);
        float var  = redm[rr][1] * (1.f / C) - mean * mean;
        float rstd = 1.f / sqrtf(var + 1e-5f);
        lnr[rr][c] = (lnr[rr][c] - mean) * rstd * gamw[c] + betw[c];
    }
    if (t < R) {
        float inv0 = inv_img[b * LV];
        float invs = inv_img[b * LV + 1 + s0 + t];
        attn_x[b * NSP + s0 + t] = redm[t][2] * inv0 * invs;
    }
    __syncthreads();
    if (t < HID) {
        float acc[8];
#pragma unroll
        for (int r = 0; r < 8; ++r) acc[r] = b1[t];
        for (int c = 0; c < C; ++c) {
            float w = w1[c * HID + t];
#pragma unroll
            for (int r = 0; r < 8; ++r) acc[r] += lnr[r][c] * w;
        }
#pragma unroll
        for (int r = 0; r < 8; ++r) HH[r][t] = gelu_exact(acc[r]);
    }
    __syncthreads();
    float scale = scale_p[0];
    if (t < 196) {
        int k = t % 49, rh = t / 49;
        for (int rr = rh; rr < 8; rr += 4) {
            if (rr < R) {
                float a = b2[k];
                for (int h = 0; h < HID; ++h) a += HH[rr][h] * w2[h * 49 + k];
                WsM[((size_t)b * NSP + s0 + rr) * 49 + k] = a * scale;
            }
        }
    }
}

// ---------------------------------------------------------------- attn_y[b,s,i] = cap_glo_i . img_sp_norm[b,s]
__global__ __launch_bounds__(64) void k_attn_y(const float* __restrict__ img,
                                               const float* __restrict__ inv_img,
                                               const float* __restrict__ gloT,
                                               float* __restrict__ attn_y) {
    int b = blockIdx.x, s0 = blockIdx.y * 8, t = threadIdx.x;
    int R = NSP - s0; if (R > 8) R = 8;
    __shared__ __align__(16) float xr[8][C];
    for (int rr = 0; rr < R; ++rr) {
        float inv = inv_img[b * LV + 1 + s0 + rr];
        const float* row = img + ((size_t)b * LV + 1 + s0 + rr) * C;
        for (int c = t; c < C; c += 64) xr[rr][c] = row[c] * inv;
    }
    __syncthreads();
    float acc[8] = {0, 0, 0, 0, 0, 0, 0, 0};
    for (int c4 = 0; c4 < C / 4; ++c4) {
        float g0 = gloT[(c4 * 4 + 0) * NCAP + t];
        float g1 = gloT[(c4 * 4 + 1) * NCAP + t];
        float g2 = gloT[(c4 * 4 + 2) * NCAP + t];
        float g3 = gloT[(c4 * 4 + 3) * NCAP + t];
#pragma unroll
        for (int r = 0; r < 8; ++r) {
            float4 xv = ((const float4*)xr[r])[c4];
            acc[r] += xv.x * g0 + xv.y * g1 + xv.z * g2 + xv.w * g3;
        }
    }
    for (int rr = 0; rr < R; ++rr)
        attn_y[((size_t)b * NSP + s0 + rr) * NCAP + t] = acc[rr];
}

// ---------------------------------------------------------------- per-pair prep: rank, gather, softmax -> global
__global__ __launch_bounds__(256) void k_prep(const float* __restrict__ attn_x,
                                              const float* __restrict__ attn_y,
                                              const float* __restrict__ WsM,
                                              int* __restrict__ gKeep,
                                              int* __restrict__ gNon,
                                              float* __restrict__ gPnk,
                                              float* __restrict__ gP) {
    int i = blockIdx.x, b = blockIdx.y, t = threadIdx.x;
    int pair = b * NCAP + i;
    __shared__ float scoreS[NSP];
    __shared__ int   keepL[NKEEP];
    __shared__ int   nonL[NKEEP];
    __shared__ float snon[NKEEP];
    __shared__ float mk[KEEPED];
    __shared__ float bcast[1];

    if (t < NSP) scoreS[t] = attn_x[b * NSP + t] + attn_y[(size_t)(b * NSP + t) * NCAP + i];
    __syncthreads();
    if (t < NSP) {
        float sv = scoreS[t];
        int r = 0;
        for (int u = 0; u < NSP; ++u) {
            float o = scoreS[u];
            r += (o > sv) || (o == sv && u < t);
        }
        if (r < NKEEP) keepL[r] = t;
        else { nonL[r - NKEEP] = t; snon[r - NKEEP] = sv; }
    }
    __syncthreads();
    if (t == 0) {
        float m = -1e30f;
        for (int j = 0; j < NKEEP; ++j) m = fmaxf(m, snon[j]);
        bcast[0] = m;
    }
    __syncthreads();
    if (t < NKEEP) {
        gKeep[pair * NKEEP + t] = keepL[t];
        gNon[pair * NKEEP + t]  = nonL[t];
        gPnk[pair * NKEEP + t]  = expf(snon[t] - bcast[0]);
    }
    if (t < KEEPED) {
        float m2 = -1e30f;
        for (int j = 0; j < NKEEP; ++j)
            m2 = fmaxf(m2, WsM[((size_t)b * NSP + keepL[j]) * KEEPED + t]);
        mk[t] = m2;
    }
    __syncthreads();
    float* Pm = gP + (size_t)pair * NKEEP * 52;
    for (int f = t; f < NKEEP * KEEPED; f += 256) {
        int j = f / KEEPED, k = f - j * KEEPED;
        Pm[j * 52 + k] = expf(WsM[((size_t)b * NSP + keepL[j]) * KEEPED + k] - mk[k]);
    }
    // zero the 3-float pad of each row (k_main reads padded rows with fixed 13-wide tiles)
    for (int f = t; f < NKEEP * 3; f += 256) {
        int j = f / 3;
        Pm[j * 52 + KEEPED + (f % 3)] = 0.f;
    }
}

// ---------------------------------------------------------------- main per-pair kernel
// 512 threads: kg=t>>7 owns 13 k-rows, cx=t&127 owns cols 4cx..4cx+3.
__global__ __launch_bounds__(512, 4) void k_main(const float* __restrict__ img,
                                                 const float* __restrict__ inv_img,
                                                 const int* __restrict__ gKeep,
                                                 const int* __restrict__ gNon,
                                                 const float* __restrict__ gPnk,
                                                 const float* __restrict__ gP,
                                                 const float* __restrict__ capn,
                                                 const float* __restrict__ qi2t,
                                                 const float* __restrict__ qt2i,
                                                 const float* __restrict__ temp_p,
                                                 float* __restrict__ out) {
    int i = blockIdx.x, b = blockIdx.y, t = threadIdx.x;
    int pair = b * NCAP + i;
    int lane = t & 63;
    int wu = t >> 6;              // wave 0..7
    int kg = t >> 7;              // 0..3
    int cx = t & 127;             // col group: cols 4cx..4cx+3
    int kbase = kg * 13;

    __shared__ __align__(16) float PU[NKEEP * 52];   // P (phase A) then U (epilogue): 20.4 KB
    __shared__ __align__(16) float Qs[96 * 68];      // Q chunk 96x64 (+pad): 26.1 KB
    __shared__ __align__(16) float Ss[64 * 53];      // sel_tok chunk [cc][l]: 13.6 KB
    __shared__ float wpartA[8][16];
    __shared__ float wpartE[8];
    __shared__ float invA[52];
    __shared__ float scl[2];
    __shared__ float colM[52], colZ[52], rowM[32], rowZ[32];
    __shared__ float redw[8];

    const int*   keep = gKeep + pair * NKEEP;
    const int*   nonk = gNon + pair * NKEEP;
    const float* pnk  = gPnk + pair * NKEEP;
    const float* Pg   = gP + (size_t)pair * NKEEP * 52;
    const float* imgb = img + (size_t)b * LV * C;
    const float4* imgb4 = (const float4*)imgb;       // row r: imgb4[r*128 + cx]

    // ---- stage P into LDS (coalesced float4)
    {
        const float4* src = (const float4*)Pg;
        float4* dst = (float4*)PU;
        for (int f = t; f < NKEEP * 52 / 4; f += 512) dst[f] = src[f];
    }

    float cls4[4];
    { float4 cv = imgb4[cx]; cls4[0] = cv.x; cls4[1] = cv.y; cls4[2] = cv.z; cls4[3] = cv.w; }

    // ---- extra: softmax-weighted nonkeep sum (1-ahead prefetch of the row)
    float e4[4] = {0.f, 0.f, 0.f, 0.f};
    {
        int s2 = nonk[0];
        float4 v = imgb4[(size_t)(1 + s2) * 128 + cx];
        for (int j = 0; j < NKEEP; ++j) {
            float4 vc = v;
            if (j + 1 < NKEEP) { s2 = nonk[j + 1]; v = imgb4[(size_t)(1 + s2) * 128 + cx]; }
            float w = pnk[j];
            e4[0] += w * vc.x; e4[1] += w * vc.y; e4[2] += w * vc.z; e4[3] += w * vc.w;
        }
    }
    __syncthreads();   // P staged

    // ---- aggr: acc[r][d] += P[j][kbase+r] * sel[j][4cx+d]
    float acc[13][4];
#pragma unroll
    for (int r = 0; r < 13; ++r) { acc[r][0] = 0.f; acc[r][1] = 0.f; acc[r][2] = 0.f; acc[r][3] = 0.f; }
    {
        int s2 = keep[0];
        float4 v = imgb4[(size_t)(1 + s2) * 128 + cx];
        for (int j = 0; j < NKEEP; ++j) {
            float4 vc = v;
            if (j + 1 < NKEEP) { s2 = keep[j + 1]; v = imgb4[(size_t)(1 + s2) * 128 + cx]; }
            const float* pr = &PU[j * 52 + kbase];
#pragma unroll
            for (int r = 0; r < 13; ++r) {
                float p = pr[r];
                acc[r][0] += p * vc.x; acc[r][1] += p * vc.y;
                acc[r][2] += p * vc.z; acc[r][3] += p * vc.w;
            }
        }
    }

    // ---- norms of aggr rows and extra
#pragma unroll
    for (int r = 0; r < 13; ++r) {
        float v = acc[r][0] * acc[r][0] + acc[r][1] * acc[r][1]
                + acc[r][2] * acc[r][2] + acc[r][3] * acc[r][3];
        for (int o = 32; o > 0; o >>= 1) v += __shfl_down(v, o);
        if (lane == 0) wpartA[wu][r] = v;
    }
    {
        float v = e4[0] * e4[0] + e4[1] * e4[1] + e4[2] * e4[2] + e4[3] * e4[3];
        for (int o = 32; o > 0; o >>= 1) v += __shfl_down(v, o);
        if (lane == 0) wpartE[wu] = v;
    }
    __syncthreads();
    if (t < KEEPED) {
        int g = t / 13, r = t - g * 13;
        float s = wpartA[2 * g][r] + wpartA[2 * g + 1][r];
        invA[t] = 1.f / fmaxf(sqrtf(s), 1e-12f);
    }
    if (t == KEEPED) {
        float s = 0.f;
#pragma unroll
        for (int w2 = 0; w2 < 8; ++w2) s += wpartE[w2];
        scl[0] = 1.f / fmaxf(sqrtf(s), 1e-12f);
    }
    __syncthreads();

    // scale register copies into final sel_tok values
    {
        float invE = scl[0];
        float invC = inv_img[b * LV];
#pragma unroll
        for (int r = 0; r < 13; ++r) {
            float ia = (kbase + r < KEEPED) ? invA[kbase + r] : 0.f;
            acc[r][0] *= ia; acc[r][1] *= ia; acc[r][2] *= ia; acc[r][3] *= ia;
        }
#pragma unroll
        for (int d = 0; d < 4; ++d) { e4[d] *= invE; cls4[d] *= invC; }
    }

    // ---- U = [capn; qi2t; qt2i](96 x C) @ sel_tok^T(C x 51), 8 chunks of 64 cols
    float uacc[12];
#pragma unroll
    for (int r = 0; r < 12; ++r) uacc[r] = 0.f;
    int lidx = (lane < 51) ? lane : 0;
    int qrow0 = wu * 12;

    for (int m = 0; m < 8; ++m) {
        __syncthreads();   // previous chunk compute done before overwriting Ss/Qs
        // write sel_tok chunk: thread owns chunk m == cx>>4
        if ((cx >> 4) == m) {
            int c0 = (cx & 15) * 4;
#pragma unroll
            for (int d = 0; d < 4; ++d) {
                float* Sc = &Ss[(c0 + d) * 53];
                if (kg == 0) Sc[0] = cls4[d];
#pragma unroll
                for (int r = 0; r < 13; ++r)
                    if (kbase + r < KEEPED) Sc[1 + kbase + r] = acc[r][d];
                if (kg == 3) Sc[50] = e4[d];
            }
        }
        // stage Q chunk (96 rows x 16 float4), coalesced
        for (int f = t; f < 96 * 16; f += 512) {
            int q = f >> 4, cq = f & 15;
            const float* rp = (q < 32) ? (capn + ((size_t)i * LT + q) * C)
                            : (q < 64) ? (qi2t + ((size_t)i * LT + q - 32) * C)
                                       : (qt2i + ((size_t)i * LT + q - 64) * C);
            *(float4*)&Qs[q * 68 + cq * 4] = *(const float4*)&rp[m * 64 + cq * 4];
        }
        __syncthreads();
        // compute: 16 quad-iters x (4 lane b32 S-reads + 12 broadcast b128 Q-reads + 48 fmac)
        for (int cq = 0; cq < 64; cq += 4) {
            float sv0 = Ss[(cq + 0) * 53 + lidx];
            float sv1 = Ss[(cq + 1) * 53 + lidx];
            float sv2 = Ss[(cq + 2) * 53 + lidx];
            float sv3 = Ss[(cq + 3) * 53 + lidx];
#pragma unroll
            for (int r = 0; r < 12; ++r) {
                float4 qv = *(const float4*)&Qs[(qrow0 + r) * 68 + cq];
                uacc[r] += qv.x * sv0 + qv.y * sv1 + qv.z * sv2 + qv.w * sv3;
            }
        }
    }
    __syncthreads();
    // ---- write U into PU region (P no longer needed)
    if (lane < 51) {
#pragma unroll
        for (int r = 0; r < 12; ++r) PU[(qrow0 + r) * 52 + lane] = uacc[r];
    }
    __syncthreads();

    // ---- softmax stats
    float invT = 1.f / temp_p[0];
    if (t < 51) {
        float mm = -1e30f;
        for (int u = 0; u < LT; ++u) mm = fmaxf(mm, PU[(32 + u) * 52 + t] * invT);
        float z = 0.f;
        for (int u = 0; u < LT; ++u) z += expf(PU[(32 + u) * 52 + t] * invT - mm);
        colM[t] = mm; colZ[t] = 1.f / z;
    }
    if (t >= 64 && t < 96) {
        int u = t - 64;
        float mm = -1e30f;
        for (int l = 0; l < 51; ++l) mm = fmaxf(mm, PU[(64 + u) * 52 + l] * invT);
        float z = 0.f;
        for (int l = 0; l < 51; ++l) z += expf(PU[(64 + u) * 52 + l] * invT - mm);
        rowM[u] = mm; rowZ[u] = 1.f / z;
    }
    __syncthreads();

    // ---- final reduction
    float part = 0.f;
    for (int f = t; f < LT * 51; f += 512) {
        int u = f / 51, l = f - u * 51;
        float u0 = PU[u * 52 + l];
        float c2 = (u0 > 0.f) ? u0 : 0.1f * u0;
        float av = expf(PU[(32 + u) * 52 + l] * invT - colM[l]) * colZ[l];
        float bv = expf(PU[(64 + u) * 52 + l] * invT - rowM[u]) * rowZ[u];
        part += c2 * (av * (1.f / 51.f) + bv * (1.f / 32.f));
    }
    for (int o = 32; o > 0; o >>= 1) part += __shfl_down(part, o);
    if (lane == 0) redw[wu] = part;
    __syncthreads();
    if (t == 0) {
        float s = 0.f;
#pragma unroll
        for (int w2 = 0; w2 < 8; ++w2) s += redw[w2];
        out[b * NCAP + i] = s;
    }
}

extern "C" void kernel_launch(void* const* d_in, const int* in_sizes, int n_in,
                              void* d_out, int out_size, void* d_ws, size_t ws_size,
                              hipStream_t stream) {
    const float* img        = (const float*)d_in[0];
    const float* cap        = (const float*)d_in[1];
    const float* gamw       = (const float*)d_in[3];
    const float* betw       = (const float*)d_in[4];
    const float* w1         = (const float*)d_in[5];
    const float* b1         = (const float*)d_in[6];
    const float* w2         = (const float*)d_in[7];
    const float* b2         = (const float*)d_in[8];
    const float* aggr_scale = (const float*)d_in[9];
    const float* wi2t       = (const float*)d_in[10];
    const float* bi2t       = (const float*)d_in[11];
    const float* wt2i       = (const float*)d_in[12];
    const float* bt2i       = (const float*)d_in[13];
    const float* temp       = (const float*)d_in[14];
    float* out = (float*)d_out;

    float* ws      = (float*)d_ws;
    float* inv_img = ws + OFF_INV;
    float* attn_x  = ws + OFF_ATTNX;
    float* WsM     = ws + OFF_WSMAT;
    float* capn    = ws + OFF_CAPN;
    float* qi2t    = ws + OFF_QI2T;
    float* qt2i    = ws + OFF_QT2I;
    float* gloT    = ws + OFF_GLOT;
    float* attn_y  = ws + OFF_ATTNY;
    int*   gKeep   = (int*)(ws + OFF_KEEP);
    int*   gNon    = (int*)(ws + OFF_NON);
    float* gPnk    = ws + OFF_PNK;
    float* gP      = ws + OFF_GP;

    k_img_norm<<<dim3(B * LV), dim3(64), 0, stream>>>(img, inv_img);
    k_cap_norm<<<dim3(NCAP, LT), dim3(64), 0, stream>>>(cap, capn, gloT);
    k_qproj<<<dim3(NCAP, 4), dim3(256), 0, stream>>>(capn, wi2t, bi2t, wt2i, bt2i, qi2t, qt2i);
    k_img_row<<<dim3(B, 25), dim3(256), 0, stream>>>(img, inv_img, gamw, betw, w1, b1, w2, b2,
                                                     aggr_scale, attn_x, WsM);
    k_attn_y<<<dim3(B, 25), dim3(64), 0, stream>>>(img, inv_img, gloT, attn_y);
    k_prep<<<dim3(NCAP, B), dim3(256), 0, stream>>>(attn_x, attn_y, WsM, gKeep, gNon, gPnk, gP);
    k_main<<<dim3(NCAP, B), dim3(512), 0, stream>>>(img, inv_img, gKeep, gNon, gPnk, gP,
                                                    capn, qi2t, qt2i, temp, out);
}